// Round 3
// baseline (30.158 us; speedup 1.0000x reference)
//
#include <hip/hip_runtime.h>
#include <hip/hip_bf16.h>

// LengthRegulator, fully fused single kernel.
// out[b, j, :] = x[b, tok(j), :] where tok(j) is the token whose
// rounded-duration cumulative interval contains j.
//
// One block per (b, t) input token. The block redundantly computes
// end = sum(counts[b, 0..t]) via a block reduction over the (L2-resident)
// dur row, derives start = end - count[t], then broadcast-writes its x row
// to output rows [start, end). x is read from HBM exactly once (25 MB),
// writes are the compulsory 100.7 MB; dur re-reads are L2-served (~32 MB L2).
// No inter-block dependencies -> deterministic, no scan kernel, no bubble.
// B=16, T=1024, D=384, T_OUT=4096 (fixed by the reference).

#define LR_B     16
#define LR_T     1024
#define LR_D4    96      // 384 floats = 96 float4 per row
#define LR_TOUT  4096
#define LR_NTHR  384     // 6 waves

__device__ __forceinline__ int lr_count(float d) {
    return (int)floorf(fmaxf(d, 0.0f) + 0.5f);
}

__global__ __launch_bounds__(LR_NTHR) void lr_fused(
    const float* __restrict__ dur, const float4* __restrict__ x,
    float4* __restrict__ out) {
    const int blk = blockIdx.x;          // b * T + t
    const int b   = blk >> 10;
    const int t   = blk & (LR_T - 1);
    const int tid = threadIdx.x;

    // Issue the x-row load early; it's independent of the reduction.
    const int g = tid / LR_D4;           // 0..3 row-slot group
    const int d = tid - g * LR_D4;
    const float4 v = x[(size_t)(b * LR_T + t) * LR_D4 + d];

    // end = sum of rounded counts over tokens 0..t (block reduction).
    const float* drow = dur + b * LR_T;
    int sum = 0;
    #pragma unroll
    for (int k = 0; k < 3; ++k) {        // 3*384 = 1152 >= 1024
        int j = tid + k * LR_NTHR;
        if (j <= t) sum += lr_count(drow[j]);
    }
    #pragma unroll
    for (int off = 1; off < 64; off <<= 1)
        sum += __shfl_xor(sum, off, 64);

    __shared__ int wsum[LR_NTHR / 64];
    if ((tid & 63) == 0) wsum[tid >> 6] = sum;
    __syncthreads();
    int end = wsum[0];
    #pragma unroll
    for (int w = 1; w < LR_NTHR / 64; ++w) end += wsum[w];

    // This token's own count (broadcast load, uniform across block).
    const int c = lr_count(drow[t]);
    int start = min(end - c, LR_TOUT);
    end = (t == LR_T - 1) ? LR_TOUT : min(end, LR_TOUT);  // searchsorted+clip tail
    if (start >= end) return;

    float4* orow = out + (size_t)b * LR_TOUT * LR_D4 + d;
    for (int p = start + g; p < end; p += 4)
        orow[(size_t)p * LR_D4] = v;
}

extern "C" void kernel_launch(void* const* d_in, const int* in_sizes, int n_in,
                              void* d_out, int out_size, void* d_ws, size_t ws_size,
                              hipStream_t stream) {
    const float* x   = (const float*)d_in[0];   // [B, T, D] fp32
    const float* dur = (const float*)d_in[1];   // [B, T]    fp32
    // d_in[2] = out_len scalar (known: 4096)

    lr_fused<<<LR_B * LR_T, LR_NTHR, 0, stream>>>(
        dur, (const float4*)d_in[0], (float4*)d_out);
}

// Round 4
// 26.106 us; speedup vs baseline: 1.1552x; 1.1552x over previous
//
#include <hip/hip_runtime.h>
#include <hip/hip_bf16.h>

// LengthRegulator, single fused kernel, chunk-amortized prefix.
// out[b, j, :] = x[b, tok(j), :] where tok(j) is the token whose
// rounded-duration cumulative interval contains j.
//
// Grid: 16 batch rows x 64 chunks = 1024 blocks; each block owns 16 tokens.
// Per block: ONE redundant reduction of counts[0..t0) for the chunk base
// (amortized 16x vs round-3's per-token version), a 16-lane shfl scan for
// within-chunk csum, then broadcast-write each token's x row to its output
// interval. x read once from HBM (25 MB); writes compulsory (100.7 MB);
// no second dispatch, no graph bubble, no inter-block deps (deterministic).
// B=16, T=1024, D=384, T_OUT=4096 (fixed by the reference).

#define LR_B     16
#define LR_T     1024
#define LR_D4    96      // 384 floats = 96 float4 per row
#define LR_TOUT  4096
#define LR_CHUNK 16      // tokens per block
#define LR_NCH   (LR_T / LR_CHUNK)   // 64 chunks per row
#define LR_NTHR  384     // 6 waves: 96 float4-lanes x 4 row-slot groups

__device__ __forceinline__ int lr_count(float d) {
    return (int)floorf(fmaxf(d, 0.0f) + 0.5f);
}

__global__ __launch_bounds__(LR_NTHR) void lr_fused(
    const float* __restrict__ dur, const float4* __restrict__ x,
    float4* __restrict__ out) {
    const int blk  = blockIdx.x;         // b * 64 + c
    const int b    = blk >> 6;
    const int c    = blk & (LR_NCH - 1);
    const int t0   = c * LR_CHUNK;
    const int tid  = threadIdx.x;
    const int lane = tid & 63;
    const int wid  = tid >> 6;

    const float* drow = dur + b * LR_T;

    // ---- base = sum of counts[0 .. t0-1] (block reduction, predicated) ----
    int sum = 0;
    #pragma unroll
    for (int k = 0; k < 3; ++k) {        // 3*384 = 1152 >= 1008 max needed
        int j = tid + k * LR_NTHR;
        if (j < t0) sum += lr_count(drow[j]);
    }
    #pragma unroll
    for (int off = 1; off < 64; off <<= 1)
        sum += __shfl_xor(sum, off, 64);

    __shared__ int wsum[LR_NTHR / 64];
    __shared__ int cs[LR_CHUNK + 1];     // cs[0]=base, cs[i+1]=incl prefix
    if (lane == 0) wsum[wid] = sum;
    __syncthreads();

    // ---- within-chunk inclusive scan of the 16 counts (wave 0) ----
    if (wid == 0) {
        int base = 0;
        #pragma unroll
        for (int w = 0; w < LR_NTHR / 64; ++w) base += wsum[w];
        if (lane < LR_CHUNK) {
            int v = lr_count(drow[t0 + lane]);
            #pragma unroll
            for (int off = 1; off < LR_CHUNK; off <<= 1) {
                int u = __shfl_up(v, off, 64);
                if (lane >= off) v += u;
            }
            cs[lane + 1] = base + v;
            if (lane == 0) cs[0] = base;
        }
    }
    __syncthreads();

    // ---- broadcast-write each token's row to its interval ----
    const int g = tid / LR_D4;           // 0..3 row-slot group
    const int d = tid - g * LR_D4;
    const float4* xrow = x + (size_t)(b * LR_T + t0) * LR_D4 + d;
    float4* orow = out + (size_t)b * LR_TOUT * LR_D4 + d;

    #pragma unroll
    for (int i = 0; i < LR_CHUNK; ++i) {
        int s = min(cs[i], LR_TOUT);
        int e = min(cs[i + 1], LR_TOUT);
        if (c == LR_NCH - 1 && i == LR_CHUNK - 1) e = LR_TOUT;  // tail: searchsorted+clip
        const float4 v = xrow[i * LR_D4];
        for (int p = s + g; p < e; p += 4)
            orow[(size_t)p * LR_D4] = v;
    }
}

extern "C" void kernel_launch(void* const* d_in, const int* in_sizes, int n_in,
                              void* d_out, int out_size, void* d_ws, size_t ws_size,
                              hipStream_t stream) {
    const float* x   = (const float*)d_in[0];   // [B, T, D] fp32
    const float* dur = (const float*)d_in[1];   // [B, T]    fp32
    // d_in[2] = out_len scalar (known: 4096)

    lr_fused<<<LR_B * LR_NCH, LR_NTHR, 0, stream>>>(
        dur, (const float4*)x, (float4*)d_out);
}

// Round 6
// 24.648 us; speedup vs baseline: 1.2235x; 1.0591x over previous
//
#include <hip/hip_runtime.h>
#include <hip/hip_bf16.h>

// LengthRegulator, single fused kernel, OUTPUT-partitioned for uniform work.
// out[b, j, :] = x[b, tok(j), :], tok(j) = searchsorted_right(csum, j) clipped.
//
// Grid: 16 batch rows x 64 windows = 1024 blocks; each block owns a fixed
// 64-row output window (96 KB contiguous). Per block:
//   1. full csum of the dur row into LDS (float4 loads, two-level shfl scan)
//   2. 64 parallel binary searches -> per-row token table in LDS
//   3. uniform store loop: EXACTLY 16 iterations per thread, no divergence,
//      6 KB contiguous per block-iteration, nontemporal (streaming) stores.
// Writes compulsory 100.7 MB, perfectly balanced; reads ~25-30 MB (L2 reuse).
// searchsorted+clip tail semantics fall out of the binary search naturally.
// B=16, T=1024, D=384, T_OUT=4096 (fixed by the reference).

#define LR_B     16
#define LR_T     1024
#define LR_D4    96      // 384 floats = 96 float4 per row
#define LR_TOUT  4096
#define LR_WIN   64      // output rows per block
#define LR_NWIN  (LR_TOUT / LR_WIN)   // 64 windows per batch row
#define LR_NTHR  384     // 6 waves: 96 float4-lanes x 4 row-slot groups

typedef float lr_f4 __attribute__((ext_vector_type(4)));  // nontemporal-compatible

__device__ __forceinline__ int lr_count(float d) {
    return (int)floorf(fmaxf(d, 0.0f) + 0.5f);
}

__global__ __launch_bounds__(LR_NTHR) void lr_fused(
    const float* __restrict__ dur, const lr_f4* __restrict__ x,
    lr_f4* __restrict__ out) {
    const int blk  = blockIdx.x;         // b * 64 + w
    const int b    = blk >> 6;
    const int w    = blk & (LR_NWIN - 1);
    const int o0   = w * LR_WIN;
    const int tid  = threadIdx.x;
    const int lane = tid & 63;
    const int wid  = tid >> 6;

    __shared__ int cs[LR_T];             // inclusive csum of rounded counts
    __shared__ int tok[LR_WIN];          // token index per output row in window
    __shared__ int wbase[4];             // per-wave scan partials (waves 0..3)

    // ---- phase 1: csum of row b into LDS ----
    const lr_f4* drow4 = (const lr_f4*)(dur + b * LR_T);
    int c0 = 0, c1 = 0, c2 = 0, c3 = 0, s = 0;
    if (tid < LR_T / 4) {                // threads 0..255, one float4 each
        lr_f4 dv = drow4[tid];
        c0 = lr_count(dv.x);
        c1 = c0 + lr_count(dv.y);
        c2 = c1 + lr_count(dv.z);
        c3 = c2 + lr_count(dv.w);
        s = c3;
    }
    int v = s;                           // inclusive wave scan of thread sums
    #pragma unroll
    for (int off = 1; off < 64; off <<= 1) {
        int u = __shfl_up(v, off, 64);
        if (lane >= off) v += u;
    }
    if (tid < LR_T / 4 && lane == 63) wbase[wid] = v;
    __syncthreads();
    if (tid < LR_T / 4) {
        int base = v - s;                // exclusive within wave
        #pragma unroll
        for (int ww = 0; ww < 4; ++ww)
            if (ww < wid) base += wbase[ww];
        int4 cw = make_int4(base + c0, base + c1, base + c2, base + c3);
        *(int4*)&cs[tid * 4] = cw;
    }
    __syncthreads();

    // ---- phase 2: per-row token via binary search (searchsorted right) ----
    if (tid < LR_WIN) {
        const int j = o0 + tid;
        int lo = 0, hi = LR_T;
        while (lo < hi) {
            int mid = (lo + hi) >> 1;
            if (cs[mid] <= j) lo = mid + 1; else hi = mid;
        }
        tok[tid] = min(lo, LR_T - 1);    // clip == reference tail semantics
    }
    __syncthreads();

    // ---- phase 3: uniform copy loop (16 iterations, no divergence) ----
    const int g = tid / LR_D4;           // 0..3: row within 4-row slab
    const int d = tid - g * LR_D4;
    const lr_f4* xb = x + (size_t)b * LR_T * LR_D4 + d;
    lr_f4* ob = out + ((size_t)b * LR_TOUT + o0 + g) * LR_D4 + d;

    #pragma unroll
    for (int it = 0; it < LR_WIN / 4; ++it) {
        const int t = tok[it * 4 + g];   // uniform within each 96-lane group
        lr_f4 val = xb[(size_t)t * LR_D4];
        __builtin_nontemporal_store(val, &ob[(size_t)it * 4 * LR_D4]);
    }
}

extern "C" void kernel_launch(void* const* d_in, const int* in_sizes, int n_in,
                              void* d_out, int out_size, void* d_ws, size_t ws_size,
                              hipStream_t stream) {
    const float* x   = (const float*)d_in[0];   // [B, T, D] fp32
    const float* dur = (const float*)d_in[1];   // [B, T]    fp32
    // d_in[2] = out_len scalar (known: 4096)

    lr_fused<<<LR_B * LR_NWIN, LR_NTHR, 0, stream>>>(
        dur, (const lr_f4*)x, (lr_f4*)d_out);
}

// Round 7
// 24.326 us; speedup vs baseline: 1.2397x; 1.0132x over previous
//
#include <hip/hip_runtime.h>
#include <hip/hip_bf16.h>

// LengthRegulator, single fused kernel, OUTPUT-partitioned, scatter-tok.
// out[b, j, :] = x[b, tok(j), :], tok(j) = searchsorted_right(csum, j) clipped.
//
// Grid: 16 batch rows x 64 windows = 1024 blocks; each block owns a fixed
// 64-row output window (96 KB contiguous). Per block:
//   1. scan: 256 threads load dur row (float4), wave shfl-scan + cross-wave
//      combine -> each scan thread holds its 4 tokens' csum in REGISTERS.
//   2. scatter: each scan thread writes tok[p-o0]=t for its intervals'
//      intersection with the window (intervals partition [0,T_OUT); no
//      binary search, no cs[] LDS array, no dependent-load chain).
//   3. uniform store loop: EXACTLY 16 iterations per thread, no divergence,
//      6 KB contiguous per block-iteration, nontemporal streaming stores.
// 2 barriers total. Writes compulsory 100.7 MB, perfectly balanced.
// B=16, T=1024, D=384, T_OUT=4096 (fixed by the reference).

#define LR_B     16
#define LR_T     1024
#define LR_D4    96      // 384 floats = 96 float4 per row
#define LR_TOUT  4096
#define LR_WIN   64      // output rows per block
#define LR_NWIN  (LR_TOUT / LR_WIN)   // 64 windows per batch row
#define LR_NTHR  384     // 6 waves: 96 float4-lanes x 4 row-slot groups

typedef float lr_f4 __attribute__((ext_vector_type(4)));

__device__ __forceinline__ int lr_count(float d) {
    return (int)floorf(fmaxf(d, 0.0f) + 0.5f);
}

__global__ __launch_bounds__(LR_NTHR) void lr_fused(
    const float* __restrict__ dur, const lr_f4* __restrict__ x,
    lr_f4* __restrict__ out) {
    const int blk  = blockIdx.x;         // b * 64 + w
    const int b    = blk >> 6;
    const int w    = blk & (LR_NWIN - 1);
    const int o0   = w * LR_WIN;
    const int tid  = threadIdx.x;
    const int lane = tid & 63;
    const int wid  = tid >> 6;

    __shared__ int tok[LR_WIN];          // token index per output row in window
    __shared__ int wbase[4];             // per-wave scan partials (waves 0..3)

    // ---- phase 1: csum of row b, kept in scan-thread registers ----
    const lr_f4* drow4 = (const lr_f4*)(dur + b * LR_T);
    int c0 = 0, c1 = 0, c2 = 0, c3 = 0, s = 0;
    if (tid < LR_T / 4) {                // threads 0..255, one float4 each
        lr_f4 dv = drow4[tid];
        c0 = lr_count(dv.x);
        c1 = c0 + lr_count(dv.y);
        c2 = c1 + lr_count(dv.z);
        c3 = c2 + lr_count(dv.w);
        s = c3;
    }
    int v = s;                           // inclusive wave scan of thread sums
    #pragma unroll
    for (int off = 1; off < 64; off <<= 1) {
        int u = __shfl_up(v, off, 64);
        if (lane >= off) v += u;
    }
    if (tid < LR_T / 4 && lane == 63) wbase[wid] = v;
    __syncthreads();

    // ---- phase 2: scatter token ids into the window's tok[] table ----
    if (tid < LR_T / 4) {
        int base = v - s;                // exclusive prefix within wave
        #pragma unroll
        for (int ww = 0; ww < 4; ++ww)
            if (ww < wid) base += wbase[ww];
        int pr = base;                   // running interval start
        const int e0 = base + c0, e1 = base + c1, e2 = base + c2, e3 = base + c3;
        const int ends[4] = {e0, e1, e2, e3};
        #pragma unroll
        for (int k = 0; k < 4; ++k) {
            const int t = tid * 4 + k;
            int st = pr, en = ends[k];
            pr = en;
            if (t == LR_T - 1) en = LR_TOUT;   // tail: searchsorted+clip
            int lo = max(st, o0), hi = min(en, o0 + LR_WIN);
            for (int p = lo; p < hi; ++p) tok[p - o0] = t;
        }
    }
    __syncthreads();

    // ---- phase 3: uniform copy loop (16 iterations, no divergence) ----
    const int g = tid / LR_D4;           // 0..3: row within 4-row slab
    const int d = tid - g * LR_D4;
    const lr_f4* xb = x + (size_t)b * LR_T * LR_D4 + d;
    lr_f4* ob = out + ((size_t)b * LR_TOUT + o0 + g) * LR_D4 + d;

    #pragma unroll
    for (int it = 0; it < LR_WIN / 4; ++it) {
        const int t = tok[it * 4 + g];   // uniform within each 96-lane group
        lr_f4 val = xb[(size_t)t * LR_D4];
        __builtin_nontemporal_store(val, &ob[(size_t)it * 4 * LR_D4]);
    }
}

extern "C" void kernel_launch(void* const* d_in, const int* in_sizes, int n_in,
                              void* d_out, int out_size, void* d_ws, size_t ws_size,
                              hipStream_t stream) {
    const float* x   = (const float*)d_in[0];   // [B, T, D] fp32
    const float* dur = (const float*)d_in[1];   // [B, T]    fp32
    // d_in[2] = out_len scalar (known: 4096)

    lr_fused<<<LR_B * LR_NWIN, LR_NTHR, 0, stream>>>(
        dur, (const lr_f4*)x, (lr_f4*)d_out);
}